// Round 2
// baseline (680.018 us; speedup 1.0000x reference)
//
#include <hip/hip_runtime.h>
#include <hip/hip_bf16.h>

// Problem: y[b,o] = sum_i x[b,i] * W[i,o] * w_mask[b,i,o] + bias[o]*b_mask[b,o]
// B=32, IN_F=1024, OUT_F=4096. ALL float tensors are float32 (reference dtype;
// round-1 NaN proved bf16 misinterpretation), masks are int32 (bool -> int*).
//
// Memory-bound on w_mask (int32, 512 MiB read-once). Design:
//  - 1 thread per output element; 512 blocks x 256 threads = 8 waves/CU.
//  - Lanes map to consecutive o -> coalesced 256 B/instr mask+weight reads.
//  - x[b,:] staged in LDS (one b per block); broadcast ds_read in loop.
//  - unroll 8 keeps ~24 KiB/CU of loads in flight (covers ~900cy HBM latency).

#define B_DIM 32
#define IN_F 1024
#define OUT_F 4096

__global__ __launch_bounds__(256) void dropout_linear_kernel(
    const float* __restrict__ x,       // [B, IN_F] f32
    const float* __restrict__ weight,  // [IN_F, OUT_F] f32
    const float* __restrict__ bias,    // [OUT_F] f32
    const int* __restrict__ w_mask,    // [B, IN_F, OUT_F] int32 0/1
    const int* __restrict__ b_mask,    // [B, OUT_F] int32 0/1
    float* __restrict__ out)           // [B, OUT_F] f32
{
    const int tid = blockIdx.x * blockDim.x + threadIdx.x;  // [0, B*OUT_F)
    const int o = tid & (OUT_F - 1);
    const int b = tid >> 12;  // log2(OUT_F) = 12; one b per 256-thread block

    // Stage x[b, :] into LDS (4 KiB).
    __shared__ float xs[IN_F];
    const float* xrow = x + b * IN_F;
    for (int i = threadIdx.x; i < IN_F; i += 256) {
        xs[i] = xrow[i];
    }
    __syncthreads();

    const int* __restrict__ mcol =
        w_mask + (size_t)b * (size_t)IN_F * (size_t)OUT_F + o;
    const float* __restrict__ wcol = weight + o;

    float acc = 0.0f;
#pragma unroll 8
    for (int i = 0; i < IN_F; ++i) {
        const float xi = xs[i];  // wave-uniform address -> LDS broadcast
        const float wi = wcol[(size_t)i * OUT_F];
        const float mi = (float)mcol[(size_t)i * OUT_F];
        acc = fmaf(xi * mi, wi, acc);
    }

    const float bm = (float)b_mask[tid];  // b*OUT_F + o == tid
    out[tid] = fmaf(bias[o], bm, acc);
}

extern "C" void kernel_launch(void* const* d_in, const int* in_sizes, int n_in,
                              void* d_out, int out_size, void* d_ws, size_t ws_size,
                              hipStream_t stream) {
    const float* x      = (const float*)d_in[0];
    const float* weight = (const float*)d_in[1];
    const float* bias   = (const float*)d_in[2];
    const int*   w_mask = (const int*)d_in[3];
    const int*   b_mask = (const int*)d_in[4];
    float* out = (float*)d_out;

    const int total = B_DIM * OUT_F;  // 131072 == out_size
    dropout_linear_kernel<<<total / 256, 256, 0, stream>>>(
        x, weight, bias, w_mask, b_mask, out);
}